// Round 1
// 668.077 us; speedup vs baseline: 1.0643x; 1.0643x over previous
//
#include <hip/hip_runtime.h>

#define THREADS 256
#define BTHREADS 1024         // bucket_step block size
#define SCTHREADS 1024        // scatter block size
#define BSHIFT 11
#define BSIZE 2048            // neurons per bucket (8KB LDS fp32 accumulator)
#define NBMAX 512             // max buckets (N <= 2^20 -> <= 512)
#define PASS_EDGES 8192       // edges sorted per pass (64 KB LDS stage)
#define EPT 8                 // edges per thread per pass (1024*8 = 8192)
#define NPMAX 2560            // max passes the bucket kernel can stage (u16 x2 = 10KB LDS)
typedef unsigned int u32;
typedef unsigned short u16;
typedef unsigned long long u64;

// ---------------- fast path: per-pass sorted runs + directory ----------------

// v[i] = x[i] for inputs else 0 ; nxt[i] = bias-init (step-0 accumulator)
__global__ void prep_kernel(const float* __restrict__ x, const float* __restrict__ bias,
                            float* __restrict__ v, float* __restrict__ nxt,
                            int N, int IN) {
    int i = blockIdx.x * THREADS + threadIdx.x;
    if (i >= N) return;
    v[i]   = (i < IN) ? x[i] : 0.0f;
    nxt[i] = (i < IN) ? 0.0f : bias[i - IN];
}

// in-place: v = isOutput ? v : tanh(v)
__global__ void finalize0_kernel(float* __restrict__ v, int N, int OUT) {
    int i = blockIdx.x * THREADS + threadIdx.x;
    if (i >= N) return;
    float val = v[i];
    v[i] = (i >= N - OUT) ? val : tanhf(val);
}

// Per 8K-edge pass: in-LDS counting sort by dst-bucket, write the sorted pass
// back to its OWN aligned slot e8[ps..ps+cnt) (streaming, zero amplification),
// plus a u16 directory row of run boundaries. Step-0 (src<IN, ~0.4% of edges)
// is fused here since src/dst/w are already in registers.
__global__ void __launch_bounds__(SCTHREADS)
scatter_kernel(const int* __restrict__ src, const int* __restrict__ dst,
               const float* __restrict__ w,
               const float* __restrict__ vA,   // step-0 input state
               float* __restrict__ vB,         // step-0 accumulator (bias-init)
               uint2* __restrict__ e8, u16* __restrict__ dir,
               int E, int IN, int NB, int NP) {
    __shared__ uint2 stage[PASS_EDGES];     // 64 KB
    __shared__ u32 hc[NBMAX];               // histogram, then rank counter
    __shared__ u32 runStart[NBMAX + 1];     // exclusive scan of hc

    const int tid = threadIdx.x;
    for (int i = tid; i < NBMAX; i += SCTHREADS) hc[i] = 0;
    __syncthreads();

    for (int p = blockIdx.x; p < NP; p += gridDim.x) {
        int ps = p * PASS_EDGES;
        int pe = ps + PASS_EDGES; if (pe > E) pe = E;
        int cntAll = pe - ps;

        // ---- load up to EPT edges into registers (+ fused step-0) ----
        int base = ps + tid * EPT;
        u32 pk[EPT]; u32 bk[EPT]; u32 wb[EPT];
        int cnt = 0;
        if (base + EPT <= pe) {
            int4 s0 = *(const int4*)(src + base), s1 = *(const int4*)(src + base + 4);
            int4 d0 = *(const int4*)(dst + base), d1 = *(const int4*)(dst + base + 4);
            float4 w0 = *(const float4*)(w + base), w1 = *(const float4*)(w + base + 4);
            int ss[EPT] = {s0.x, s0.y, s0.z, s0.w, s1.x, s1.y, s1.z, s1.w};
            int dd[EPT] = {d0.x, d0.y, d0.z, d0.w, d1.x, d1.y, d1.z, d1.w};
            float ww[EPT] = {w0.x, w0.y, w0.z, w0.w, w1.x, w1.y, w1.z, w1.w};
            cnt = EPT;
            #pragma unroll
            for (int i = 0; i < EPT; ++i) {
                u32 d = (u32)dd[i];
                bk[i] = d >> BSHIFT;
                pk[i] = (u32)ss[i] | ((d & (BSIZE - 1u)) << 20);
                wb[i] = __float_as_uint(ww[i]);
                if (ss[i] < IN) atomicAdd(&vB[dd[i]], vA[ss[i]] * ww[i]);
            }
        } else {
            for (int i = 0; i < EPT; ++i) {
                int e = base + i;
                if (e < pe) {
                    int s = src[e];
                    u32 d = (u32)dst[e];
                    float wv = w[e];
                    bk[cnt] = d >> BSHIFT;
                    pk[cnt] = (u32)s | ((d & (BSIZE - 1u)) << 20);
                    wb[cnt] = __float_as_uint(wv);
                    if (s < IN) atomicAdd(&vB[d], vA[s] * wv);
                    ++cnt;
                }
            }
        }

        // ---- histogram (hc zeroed at init / end of previous pass) ----
        for (int i = 0; i < cnt; ++i) atomicAdd(&hc[bk[i]], 1u);
        __syncthreads();

        // ---- single-wave shuffle scan over NBMAX entries; zero hc for ranking ----
        if (tid < 64) {
            u32 c[8]; u32 s = 0;
            #pragma unroll
            for (int k = 0; k < 8; ++k) { c[k] = hc[tid * 8 + k]; s += c[k]; }
            u32 inc = s;
            #pragma unroll
            for (int off = 1; off < 64; off <<= 1) {
                u32 t = __shfl_up(inc, off, 64);
                if (tid >= off) inc += t;
            }
            u32 excl = inc - s;
            #pragma unroll
            for (int k = 0; k < 8; ++k) {
                runStart[tid * 8 + k] = excl;
                excl += c[k];
                hc[tid * 8 + k] = 0;           // rank counters
            }
            if (tid == 63) runStart[NBMAX] = excl;   // == cntAll
        }
        __syncthreads();

        // ---- ranked placement into LDS (counting sort) ----
        for (int i = 0; i < cnt; ++i) {
            u32 b = bk[i];
            u32 r = atomicAdd(&hc[b], 1u);
            stage[runStart[b] + r] = make_uint2(pk[i], wb[i]);
        }
        __syncthreads();

        // ---- aligned streaming copy-out + directory row + hc re-zero ----
        for (int j = tid * 2; j + 1 < cntAll; j += SCTHREADS * 2)
            *(uint4*)(e8 + ps + j) = *(const uint4*)(stage + j);
        if ((cntAll & 1) && tid == 0) e8[ps + cntAll - 1] = stage[cntAll - 1];
        if (tid <= NB) dir[(u32)p * (u32)(NB + 1) + tid] = (u16)runStart[tid];
        if (tid < NBMAX) hc[tid] = 0;            // placement counts -> zero for next pass
        __syncthreads();                          // protect stage/runStart/hc
    }
}

// one block per bucket: walk this bucket's run in every pass via the directory.
// 16-lane subgroups matched to the ~16-edge mean run length.
__global__ void __launch_bounds__(BTHREADS)
bucket_step_kernel(const uint2* __restrict__ e8, const u16* __restrict__ dir,
                   const float* __restrict__ v_in, float* __restrict__ v_out,
                   const float* __restrict__ bias,
                   float* __restrict__ out,   // null except last step
                   int N, int IN, int OUT, int NB, int NP) {
    __shared__ float acc[BSIZE];                // 8 KB
    __shared__ u16 rs[NPMAX], re[NPMAX];        // 10 KB run boundaries
    const int tid = threadIdx.x;
    const int b = blockIdx.x;

    for (int p = tid; p < NP; p += BTHREADS) {
        const u16* row = dir + (u32)p * (u32)(NB + 1) + b;
        rs[p] = row[0];
        re[p] = row[1];
    }
    for (int i = tid; i < BSIZE; i += BTHREADS) acc[i] = 0.0f;
    __syncthreads();

    const int sg = tid >> 4, ln = tid & 15;     // 64 subgroups of 16 lanes
    for (int p = sg; p < NP; p += BTHREADS >> 4) {
        int s0 = rs[p], s1 = re[p];
        int base = p * PASS_EDGES;
        for (int j = s0 + ln; j < s1; j += 16) {
            // nontemporal: e8 is a single-use stream; keep v_in resident in L2
            u64 pv = __builtin_nontemporal_load((const u64*)(e8 + base + j));
            u32 px = (u32)pv;
            float pw = __uint_as_float((u32)(pv >> 32));
            atomicAdd(&acc[px >> 20], v_in[px & 0xFFFFFu] * pw);
        }
    }
    __syncthreads();

    int nbase = b << BSHIFT;
    for (int j = tid; j < BSIZE; j += BTHREADS) {
        int idx = nbase + j;
        if (idx >= N) break;
        float val = acc[j] + (idx >= IN ? bias[idx - IN] : 0.0f);
        bool isOut = idx >= N - OUT;
        float a = isOut ? val : tanhf(val);
        v_out[idx] = a;
        if (out != nullptr && isOut) out[idx - (N - OUT)] = a;
    }
}

// ---------------- fallback path (atomic version) ----------------

__global__ void edge_kernel(const int* __restrict__ src, const int* __restrict__ dst,
                            const float* __restrict__ w, const float* __restrict__ v,
                            float* __restrict__ nxt, int E) {
    int k = blockIdx.x * THREADS + threadIdx.x;
    int E4 = E >> 2;
    if (k < E4) {
        int4 s = ((const int4*)src)[k];
        int4 d = ((const int4*)dst)[k];
        float4 wv = ((const float4*)w)[k];
        atomicAdd(&nxt[d.x], v[s.x] * wv.x);
        atomicAdd(&nxt[d.y], v[s.y] * wv.y);
        atomicAdd(&nxt[d.z], v[s.z] * wv.z);
        atomicAdd(&nxt[d.w], v[s.w] * wv.w);
    }
    if (k == 0) {
        for (int e = E4 << 2; e < E; ++e)
            atomicAdd(&nxt[dst[e]], v[src[e]] * w[e]);
    }
}

__global__ void finalize_kernel(float* __restrict__ nxt, float* __restrict__ v,
                                const float* __restrict__ bias, float* __restrict__ out,
                                int N, int IN, int OUT) {
    int i = blockIdx.x * THREADS + threadIdx.x;
    if (i >= N) return;
    float val = nxt[i];
    bool isOut = (i >= N - OUT);
    float a = isOut ? val : tanhf(val);
    v[i] = a;
    nxt[i] = (i < IN) ? 0.0f : bias[i - IN];
    if (out != nullptr && isOut) out[i - (N - OUT)] = a;
}

// ---------------- launch ----------------

extern "C" void kernel_launch(void* const* d_in, const int* in_sizes, int n_in,
                              void* d_out, int out_size, void* d_ws, size_t ws_size,
                              hipStream_t stream) {
    const float* x    = (const float*)d_in[0];
    const float* w    = (const float*)d_in[1];
    const float* bias = (const float*)d_in[2];
    const int* src = (const int*)d_in[3];
    const int* dst = (const int*)d_in[4];

    const int IN  = in_sizes[0];
    const int E   = in_sizes[1];
    const int N   = IN + in_sizes[2];
    const int OUT = out_size;

    const int NP = (E + PASS_EDGES - 1) / PASS_EDGES;
    const int NB = (N + BSIZE - 1) >> BSHIFT;

    // workspace layout for fast path
    uint2* e8   = (uint2*)d_ws;                              // E * 8B
    u16*   dir  = (u16*)(e8 + E);                            // NP*(NB+1) u16
    size_t dirB = (size_t)NP * (size_t)(NB + 1) * sizeof(u16);
    float* vA   = (float*)((char*)dir + ((dirB + 15) & ~(size_t)15));  // N
    float* vB   = vA + N;                                    // N
    size_t need = (size_t)((char*)(vB + N) - (char*)d_ws);

    int nBlocks = (N + THREADS - 1) / THREADS;

    if (ws_size >= need && N <= (NBMAX << BSHIFT) && NP <= NPMAX) {
        // vA = input state; vB = step-0 accumulator (bias-init)
        prep_kernel<<<nBlocks, THREADS, 0, stream>>>(x, bias, vA, vB, N, IN);
        // build per-pass sorted runs + directory; fused sparse step-0
        scatter_kernel<<<512, SCTHREADS, 0, stream>>>(
            src, dst, w, vA, vB, e8, dir, E, IN, NB, NP);
        finalize0_kernel<<<nBlocks, THREADS, 0, stream>>>(vB, N, OUT);
        // steps 1,2: bucketized gather via directory
        bucket_step_kernel<<<NB, BTHREADS, 0, stream>>>(
            e8, dir, vB, vA, bias, nullptr, N, IN, OUT, NB, NP);
        bucket_step_kernel<<<NB, BTHREADS, 0, stream>>>(
            e8, dir, vA, vB, bias, (float*)d_out, N, IN, OUT, NB, NP);
    } else {
        // fallback: atomic implementation
        float* v   = (float*)d_ws;
        float* nxt = v + N;
        int eBlocks = ((E >> 2) + THREADS - 1) / THREADS;
        prep_kernel<<<nBlocks, THREADS, 0, stream>>>(x, bias, v, nxt, N, IN);
        for (int step = 0; step < 3; ++step) {
            edge_kernel<<<eBlocks, THREADS, 0, stream>>>(src, dst, w, v, nxt, E);
            float* outp = (step == 2) ? (float*)d_out : nullptr;
            finalize_kernel<<<nBlocks, THREADS, 0, stream>>>(nxt, v, bias, outp, N, IN, OUT);
        }
    }
}

// Round 2
// 667.091 us; speedup vs baseline: 1.0659x; 1.0015x over previous
//
#include <hip/hip_runtime.h>

#define THREADS 256
#define BTHREADS 1024         // bucket_step block size
#define SCTHREADS 1024        // scatter block size
#define BSHIFT 11
#define BSIZE 2048            // neurons per sort-bucket (11-bit local id in pk)
#define NBMAX 512             // max sort-buckets (N <= 2^20 -> <= 512)
#define PASS_EDGES 8192       // edges sorted per pass (64 KB LDS stage)
#define EPT 8                 // edges per thread per pass (1024*8 = 8192)
#define G 4                   // sort-buckets per acc block (contiguous segment)
#define GSHIFT 2
#define ACCSIZE 8192          // G * BSIZE floats = 32 KB LDS accumulator
#define SPLIT 4               // pass-splits per acc block (grid = NB/G * SPLIT)
#define NPSMAX 640            // max passes per split (SPLIT*NPSMAX >= NP)
typedef unsigned int u32;
typedef unsigned short u16;
typedef unsigned long long u64;

// ---------------- fast path: per-pass sorted runs + directory ----------------

// v[i] = x[i] for inputs else 0 ; nxt[i] = bias-init (step-0 accumulator)
__global__ void prep_kernel(const float* __restrict__ x, const float* __restrict__ bias,
                            float* __restrict__ v, float* __restrict__ nxt,
                            int N, int IN) {
    int i = blockIdx.x * THREADS + threadIdx.x;
    if (i >= N) return;
    v[i]   = (i < IN) ? x[i] : 0.0f;
    nxt[i] = (i < IN) ? 0.0f : bias[i - IN];
}

// in-place: v = isOutput ? v : tanh(v)
__global__ void finalize0_kernel(float* __restrict__ v, int N, int OUT) {
    int i = blockIdx.x * THREADS + threadIdx.x;
    if (i >= N) return;
    float val = v[i];
    v[i] = (i >= N - OUT) ? val : tanhf(val);
}

// state = f(nxt + bias) in place; nxt holds raw accumulated sums (zero-init'd)
__global__ void finalize_fast_kernel(float* __restrict__ nxt, const float* __restrict__ bias,
                                     float* __restrict__ out,   // null except last step
                                     int N, int IN, int OUT) {
    int i = blockIdx.x * THREADS + threadIdx.x;
    if (i >= N) return;
    float val = nxt[i] + (i >= IN ? bias[i - IN] : 0.0f);
    bool isOut = (i >= N - OUT);
    float a = isOut ? val : tanhf(val);
    nxt[i] = a;
    if (out != nullptr && isOut) out[i - (N - OUT)] = a;
}

// Per 8K-edge pass: in-LDS counting sort by dst-bucket, write the sorted pass
// back to its OWN aligned slot e8[ps..ps+cnt) (streaming, zero amplification),
// plus a u16 directory row of run boundaries. Step-0 (src<IN, ~0.4% of edges)
// is fused here since src/dst/w are already in registers.
__global__ void __launch_bounds__(SCTHREADS)
scatter_kernel(const int* __restrict__ src, const int* __restrict__ dst,
               const float* __restrict__ w,
               const float* __restrict__ vA,   // step-0 input state
               float* __restrict__ vB,         // step-0 accumulator (bias-init)
               uint2* __restrict__ e8, u16* __restrict__ dir,
               int E, int IN, int NB, int NP) {
    __shared__ uint2 stage[PASS_EDGES];     // 64 KB
    __shared__ u32 hc[NBMAX];               // histogram, then rank counter
    __shared__ u32 runStart[NBMAX + 1];     // exclusive scan of hc

    const int tid = threadIdx.x;
    for (int i = tid; i < NBMAX; i += SCTHREADS) hc[i] = 0;
    __syncthreads();

    for (int p = blockIdx.x; p < NP; p += gridDim.x) {
        int ps = p * PASS_EDGES;
        int pe = ps + PASS_EDGES; if (pe > E) pe = E;
        int cntAll = pe - ps;

        // ---- load up to EPT edges into registers (+ fused step-0) ----
        int base = ps + tid * EPT;
        u32 pk[EPT]; u32 bk[EPT]; u32 wb[EPT];
        int cnt = 0;
        if (base + EPT <= pe) {
            int4 s0 = *(const int4*)(src + base), s1 = *(const int4*)(src + base + 4);
            int4 d0 = *(const int4*)(dst + base), d1 = *(const int4*)(dst + base + 4);
            float4 w0 = *(const float4*)(w + base), w1 = *(const float4*)(w + base + 4);
            int ss[EPT] = {s0.x, s0.y, s0.z, s0.w, s1.x, s1.y, s1.z, s1.w};
            int dd[EPT] = {d0.x, d0.y, d0.z, d0.w, d1.x, d1.y, d1.z, d1.w};
            float ww[EPT] = {w0.x, w0.y, w0.z, w0.w, w1.x, w1.y, w1.z, w1.w};
            cnt = EPT;
            #pragma unroll
            for (int i = 0; i < EPT; ++i) {
                u32 d = (u32)dd[i];
                bk[i] = d >> BSHIFT;
                pk[i] = (u32)ss[i] | ((d & (BSIZE - 1u)) << 20);
                wb[i] = __float_as_uint(ww[i]);
                if (ss[i] < IN) atomicAdd(&vB[dd[i]], vA[ss[i]] * ww[i]);
            }
        } else {
            for (int i = 0; i < EPT; ++i) {
                int e = base + i;
                if (e < pe) {
                    int s = src[e];
                    u32 d = (u32)dst[e];
                    float wv = w[e];
                    bk[cnt] = d >> BSHIFT;
                    pk[cnt] = (u32)s | ((d & (BSIZE - 1u)) << 20);
                    wb[cnt] = __float_as_uint(wv);
                    if (s < IN) atomicAdd(&vB[d], vA[s] * wv);
                    ++cnt;
                }
            }
        }

        // ---- histogram (hc zeroed at init / end of previous pass) ----
        for (int i = 0; i < cnt; ++i) atomicAdd(&hc[bk[i]], 1u);
        __syncthreads();

        // ---- single-wave shuffle scan over NBMAX entries; zero hc for ranking ----
        if (tid < 64) {
            u32 c[8]; u32 s = 0;
            #pragma unroll
            for (int k = 0; k < 8; ++k) { c[k] = hc[tid * 8 + k]; s += c[k]; }
            u32 inc = s;
            #pragma unroll
            for (int off = 1; off < 64; off <<= 1) {
                u32 t = __shfl_up(inc, off, 64);
                if (tid >= off) inc += t;
            }
            u32 excl = inc - s;
            #pragma unroll
            for (int k = 0; k < 8; ++k) {
                runStart[tid * 8 + k] = excl;
                excl += c[k];
                hc[tid * 8 + k] = 0;           // rank counters
            }
            if (tid == 63) runStart[NBMAX] = excl;   // == cntAll
        }
        __syncthreads();

        // ---- ranked placement into LDS (counting sort) ----
        for (int i = 0; i < cnt; ++i) {
            u32 b = bk[i];
            u32 r = atomicAdd(&hc[b], 1u);
            stage[runStart[b] + r] = make_uint2(pk[i], wb[i]);
        }
        __syncthreads();

        // ---- aligned streaming copy-out + directory row + hc re-zero ----
        for (int j = tid * 2; j + 1 < cntAll; j += SCTHREADS * 2)
            *(uint4*)(e8 + ps + j) = *(const uint4*)(stage + j);
        if ((cntAll & 1) && tid == 0) e8[ps + cntAll - 1] = stage[cntAll - 1];
        if (tid <= NB) dir[(u32)p * (u32)(NB + 1) + tid] = (u16)runStart[tid];
        if (tid < NBMAX) hc[tid] = 0;            // placement counts -> zero for next pass
        __syncthreads();                          // protect stage/runStart/hc
    }
}

// One block per (acc-group of G sort-buckets, pass-split). Per pass the block's
// edges are ONE CONTIGUOUS segment [dir[p][4b], dir[p][4b+4]) of mean 64 edges,
// consumed by a full wave. Sub-bucket recovered by 3 boundary compares.
// Each wave runs 4 independent pass-chains for memory-level parallelism.
__global__ void __launch_bounds__(BTHREADS)
bucket_step_kernel(const uint2* __restrict__ e8, const u16* __restrict__ dir,
                   const float* __restrict__ v_in, float* __restrict__ nxt,
                   int N, int NB, int NP) {
    __shared__ float acc[ACCSIZE];          // 32 KB
    __shared__ u16 sb[G + 1][NPSMAX];       // 6.4 KB boundary columns
    const int tid = threadIdx.x;
    const int gb = blockIdx.x >> 2;         // acc-group index (SPLIT==4)
    const int sp = blockIdx.x & 3;          // split id

    const int NPS = (NP + SPLIT - 1) / SPLIT;
    const int p0 = sp * NPS;
    int pc = NP - p0; if (pc > NPS) pc = NPS; if (pc < 0) pc = 0;

    // stage this group's 5 directory columns for our pass range
    const int b0 = gb << GSHIFT;
    for (int idx = tid; idx < pc * (G + 1); idx += BTHREADS) {
        int i = idx / (G + 1), k = idx - i * (G + 1);
        int col = b0 + k; if (col > NB) col = NB;
        sb[k][i] = dir[(u32)(p0 + i) * (u32)(NB + 1) + col];
    }
    for (int i = tid; i < ACCSIZE; i += BTHREADS) acc[i] = 0.0f;
    __syncthreads();

    const int wv = tid >> 6, ln = tid & 63;   // 16 waves
    for (int pp = wv; pp < pc; pp += 64) {    // chains: pp, pp+16, pp+32, pp+48
        int  jj[4], je[4], eb[4];
        u32  s1[4], s2[4], s3[4];
        bool act[4];
        #pragma unroll
        for (int c = 0; c < 4; ++c) {
            int i = pp + c * 16;
            act[c] = false;
            if (i < pc) {
                u32 a0 = sb[0][i];
                s1[c] = sb[1][i]; s2[c] = sb[2][i]; s3[c] = sb[3][i];
                jj[c] = (int)a0 + ln;
                je[c] = (int)sb[4][i];
                eb[c] = (p0 + i) * PASS_EDGES;
                act[c] = jj[c] < je[c];
            }
        }
        while (act[0] | act[1] | act[2] | act[3]) {
            u64 pv[4];
            #pragma unroll
            for (int c = 0; c < 4; ++c)
                if (act[c]) pv[c] = __builtin_nontemporal_load((const u64*)(e8 + eb[c] + jj[c]));
            float vv[4];
            #pragma unroll
            for (int c = 0; c < 4; ++c)
                if (act[c]) vv[c] = v_in[(u32)pv[c] & 0xFFFFFu];
            #pragma unroll
            for (int c = 0; c < 4; ++c) {
                if (act[c]) {
                    u32 px = (u32)pv[c];
                    u32 j  = (u32)jj[c];
                    u32 r  = (u32)(j >= s1[c]) + (u32)(j >= s2[c]) + (u32)(j >= s3[c]);
                    float pw = __uint_as_float((u32)(pv[c] >> 32));
                    atomicAdd(&acc[(r << BSHIFT) + (px >> 20)], vv[c] * pw);
                    jj[c] += 64;
                    act[c] = jj[c] < je[c];
                }
            }
        }
    }
    __syncthreads();

    // combine partials into global accumulator (zero-init'd)
    int nbase = b0 << BSHIFT;
    for (int j = tid; j < ACCSIZE; j += BTHREADS) {
        int idx = nbase + j;
        if (idx < N) atomicAdd(&nxt[idx], acc[j]);
    }
}

// ---------------- fallback path (atomic version) ----------------

__global__ void edge_kernel(const int* __restrict__ src, const int* __restrict__ dst,
                            const float* __restrict__ w, const float* __restrict__ v,
                            float* __restrict__ nxt, int E) {
    int k = blockIdx.x * THREADS + threadIdx.x;
    int E4 = E >> 2;
    if (k < E4) {
        int4 s = ((const int4*)src)[k];
        int4 d = ((const int4*)dst)[k];
        float4 wv = ((const float4*)w)[k];
        atomicAdd(&nxt[d.x], v[s.x] * wv.x);
        atomicAdd(&nxt[d.y], v[s.y] * wv.y);
        atomicAdd(&nxt[d.z], v[s.z] * wv.z);
        atomicAdd(&nxt[d.w], v[s.w] * wv.w);
    }
    if (k == 0) {
        for (int e = E4 << 2; e < E; ++e)
            atomicAdd(&nxt[dst[e]], v[src[e]] * w[e]);
    }
}

__global__ void finalize_kernel(float* __restrict__ nxt, float* __restrict__ v,
                                const float* __restrict__ bias, float* __restrict__ out,
                                int N, int IN, int OUT) {
    int i = blockIdx.x * THREADS + threadIdx.x;
    if (i >= N) return;
    float val = nxt[i];
    bool isOut = (i >= N - OUT);
    float a = isOut ? val : tanhf(val);
    v[i] = a;
    nxt[i] = (i < IN) ? 0.0f : bias[i - IN];
    if (out != nullptr && isOut) out[i - (N - OUT)] = a;
}

// ---------------- launch ----------------

extern "C" void kernel_launch(void* const* d_in, const int* in_sizes, int n_in,
                              void* d_out, int out_size, void* d_ws, size_t ws_size,
                              hipStream_t stream) {
    const float* x    = (const float*)d_in[0];
    const float* w    = (const float*)d_in[1];
    const float* bias = (const float*)d_in[2];
    const int* src = (const int*)d_in[3];
    const int* dst = (const int*)d_in[4];

    const int IN  = in_sizes[0];
    const int E   = in_sizes[1];
    const int N   = IN + in_sizes[2];
    const int OUT = out_size;

    const int NP = (E + PASS_EDGES - 1) / PASS_EDGES;
    const int NB = (N + BSIZE - 1) >> BSHIFT;

    // workspace layout for fast path
    uint2* e8   = (uint2*)d_ws;                              // E * 8B
    u16*   dir  = (u16*)(e8 + E);                            // NP*(NB+1) u16
    size_t dirB = (size_t)NP * (size_t)(NB + 1) * sizeof(u16);
    float* vA   = (float*)((char*)dir + ((dirB + 15) & ~(size_t)15));  // N
    float* vB   = vA + N;                                    // N
    size_t need = (size_t)((char*)(vB + N) - (char*)d_ws);

    int nBlocks = (N + THREADS - 1) / THREADS;

    if (ws_size >= need && N <= (NBMAX << BSHIFT) && NP <= SPLIT * NPSMAX) {
        const int NBG = ((NB + G - 1) >> GSHIFT);
        // vA = input state; vB = step-0 accumulator (bias-init)
        prep_kernel<<<nBlocks, THREADS, 0, stream>>>(x, bias, vA, vB, N, IN);
        // build per-pass sorted runs + directory; fused sparse step-0
        scatter_kernel<<<512, SCTHREADS, 0, stream>>>(
            src, dst, w, vA, vB, e8, dir, E, IN, NB, NP);
        finalize0_kernel<<<nBlocks, THREADS, 0, stream>>>(vB, N, OUT);   // vB = state S1
        // step 1: accumulate into vA (zeroed), then finalize in place
        hipMemsetAsync(vA, 0, (size_t)N * sizeof(float), stream);
        bucket_step_kernel<<<NBG * SPLIT, BTHREADS, 0, stream>>>(
            e8, dir, vB, vA, N, NB, NP);
        finalize_fast_kernel<<<nBlocks, THREADS, 0, stream>>>(vA, bias, nullptr, N, IN, OUT);
        // step 2: accumulate into vB (zeroed), finalize + emit outputs
        hipMemsetAsync(vB, 0, (size_t)N * sizeof(float), stream);
        bucket_step_kernel<<<NBG * SPLIT, BTHREADS, 0, stream>>>(
            e8, dir, vA, vB, N, NB, NP);
        finalize_fast_kernel<<<nBlocks, THREADS, 0, stream>>>(vB, bias, (float*)d_out, N, IN, OUT);
    } else {
        // fallback: atomic implementation
        float* v   = (float*)d_ws;
        float* nxt = v + N;
        int eBlocks = ((E >> 2) + THREADS - 1) / THREADS;
        prep_kernel<<<nBlocks, THREADS, 0, stream>>>(x, bias, v, nxt, N, IN);
        for (int step = 0; step < 3; ++step) {
            edge_kernel<<<eBlocks, THREADS, 0, stream>>>(src, dst, w, v, nxt, E);
            float* outp = (step == 2) ? (float*)d_out : nullptr;
            finalize_kernel<<<nBlocks, THREADS, 0, stream>>>(nxt, v, bias, outp, N, IN, OUT);
        }
    }
}